// Round 1
// baseline (96.506 us; speedup 1.0000x reference)
//
#include <hip/hip_runtime.h>

#define S_LEN 4096
#define DIM   64
#define HALF  50
#define ROWS  64            // query rows per block
#define THREADS 128         // 32 quads * 4 lanes; quad = 2 adjacent rows
#define KSPAN 164           // ROWS + 2*HALF
#define SCALE 0.125f        // 1/sqrt(64)

__device__ __forceinline__ unsigned int bf16_rne(float f) {
    unsigned int u = __float_as_uint(f);
    return (u + 0x7fffu + ((u >> 16) & 1u)) >> 16;
}
__device__ __forceinline__ unsigned int pack2(float lo, float hi) {
    return bf16_rne(lo) | (bf16_rne(hi) << 16);
}
__device__ __forceinline__ void unp8(uint4 u, float* f) {
    f[0] = __uint_as_float(u.x << 16); f[1] = __uint_as_float(u.x & 0xffff0000u);
    f[2] = __uint_as_float(u.y << 16); f[3] = __uint_as_float(u.y & 0xffff0000u);
    f[4] = __uint_as_float(u.z << 16); f[5] = __uint_as_float(u.z & 0xffff0000u);
    f[6] = __uint_as_float(u.w << 16); f[7] = __uint_as_float(u.w & 0xffff0000u);
}

__global__ __launch_bounds__(THREADS)
void lattn_kernel(const float* __restrict__ Q, const float* __restrict__ K,
                  const float* __restrict__ V, float* __restrict__ O) {
    // bf16 K/V window tiles, 16B slots, XOR-swizzled for conflict-free ds_read_b128
    __shared__ uint4 Ks[KSPAN * 8];
    __shared__ uint4 Vs[KSPAN * 8];

    const int bh = blockIdx.y;
    const int r0 = blockIdx.x * ROWS;
    const size_t base = (size_t)bh * S_LEN * DIM;
    const float* Qg = Q + base;
    const float* Kg = K + base;
    const float* Vg = V + base;
    float*       Og = O + base;

    const int klo = max(0, r0 - HALF);
    const int khi = min(S_LEN, r0 + ROWS + HALF);   // exclusive
    const int cnt = khi - klo;

    // ---- stage K/V window as bf16 (RNE), swizzled ----
    for (int c = threadIdx.x; c < cnt * 8; c += THREADS) {
        const int row = c >> 3, slot = c & 7;
        const int s2 = slot ^ ((row >> 1) & 7);
        const size_t g = (size_t)(klo + row) * DIM + slot * 8;
        float4 a = *(const float4*)(Kg + g);
        float4 b = *(const float4*)(Kg + g + 4);
        Ks[row * 8 + s2] = make_uint4(pack2(a.x, a.y), pack2(a.z, a.w),
                                      pack2(b.x, b.y), pack2(b.z, b.w));
        a = *(const float4*)(Vg + g);
        b = *(const float4*)(Vg + g + 4);
        Vs[row * 8 + s2] = make_uint4(pack2(a.x, a.y), pack2(a.z, a.w),
                                      pack2(b.x, b.y), pack2(b.z, b.w));
    }
    __syncthreads();

    // ---- each quad: rows (iA, iA+1); lane owns dims [16p, 16p+16) ----
    const int t  = threadIdx.x;
    const int pr = t >> 2;          // quad index 0..31
    const int p  = t & 3;           // dim-slice within quad
    const int iA = r0 + 2 * pr;
    const int iB = iA + 1;

    float qA[16], qB[16];
    {
        const float4* qa = (const float4*)(Qg + (size_t)iA * DIM + p * 16);
        const float4* qb = (const float4*)(Qg + (size_t)iB * DIM + p * 16);
        #pragma unroll
        for (int c = 0; c < 4; ++c) {
            float4 a = qa[c], b = qb[c];
            qA[4*c+0] = a.x * SCALE; qA[4*c+1] = a.y * SCALE;
            qA[4*c+2] = a.z * SCALE; qA[4*c+3] = a.w * SCALE;
            qB[4*c+0] = b.x * SCALE; qB[4*c+1] = b.y * SCALE;
            qB[4*c+2] = b.z * SCALE; qB[4*c+3] = b.w * SCALE;
        }
    }

    float accA[16], accB[16];
    #pragma unroll
    for (int c = 0; c < 16; ++c) { accA[c] = 0.f; accB[c] = 0.f; }
    float lA = 0.f, lB = 0.f;

    const int jlo   = max(0, iA - HALF);
    const int jhi   = min(S_LEN - 1, iB + HALF);
    const int jAmax = iA + HALF;
    const int jBmin = iB - HALF;

    #pragma unroll 2
    for (int j = jlo; j <= jhi; ++j) {
        const int jr = j - klo;
        const int xr = (jr >> 1) & 7;
        const uint4 k0 = Ks[jr * 8 + ((2 * p)     ^ xr)];
        const uint4 k1 = Ks[jr * 8 + ((2 * p + 1) ^ xr)];
        float kf[16];
        unp8(k0, kf); unp8(k1, kf + 8);

        float sA = 0.f, sB = 0.f;
        #pragma unroll
        for (int c = 0; c < 16; ++c) { sA += qA[c] * kf[c]; sB += qB[c] * kf[c]; }
        sA += __shfl_xor(sA, 1); sA += __shfl_xor(sA, 2);
        sB += __shfl_xor(sB, 1); sB += __shfl_xor(sB, 2);

        const float eA = __expf(fminf(sA, 60.f));
        const float eB = __expf(fminf(sB, 60.f));
        const float wA = (j <= jAmax) ? eA : 0.f;   // row A band mask
        const float wB = (j >= jBmin) ? eB : 0.f;   // row B band mask
        lA += wA; lB += wB;

        const uint4 v0 = Vs[jr * 8 + ((2 * p)     ^ xr)];
        const uint4 v1 = Vs[jr * 8 + ((2 * p + 1) ^ xr)];
        float vf[16];
        unp8(v0, vf); unp8(v1, vf + 8);
        #pragma unroll
        for (int c = 0; c < 16; ++c) {
            accA[c] += wA * vf[c];
            accB[c] += wB * vf[c];
        }
    }

    const float rA = 1.f / lA, rB = 1.f / lB;
    float* oA = Og + (size_t)iA * DIM + p * 16;
    float* oB = Og + (size_t)iB * DIM + p * 16;
    #pragma unroll
    for (int c = 0; c < 4; ++c) {
        *(float4*)(oA + 4 * c) = make_float4(accA[4*c+0] * rA, accA[4*c+1] * rA,
                                             accA[4*c+2] * rA, accA[4*c+3] * rA);
        *(float4*)(oB + 4 * c) = make_float4(accB[4*c+0] * rB, accB[4*c+1] * rB,
                                             accB[4*c+2] * rB, accB[4*c+3] * rB);
    }
}

extern "C" void kernel_launch(void* const* d_in, const int* in_sizes, int n_in,
                              void* d_out, int out_size, void* d_ws, size_t ws_size,
                              hipStream_t stream) {
    const float* q = (const float*)d_in[0];
    const float* k = (const float*)d_in[1];
    const float* v = (const float*)d_in[2];
    float* o = (float*)d_out;
    const int bhn = in_sizes[0] / (S_LEN * DIM);   // B*H = 16
    dim3 grid(S_LEN / ROWS, bhn);
    lattn_kernel<<<grid, THREADS, 0, stream>>>(q, k, v, o);
}

// Round 2
// 26.523 us; speedup vs baseline: 3.6386x; 3.6386x over previous
//
#include <hip/hip_runtime.h>

#define S_LEN 4096
#define DIM   64
#define HALF  50
#define RB    64            // query rows per block
#define WQ    16            // query rows per wave (4 waves)
#define THREADS 256
#define KCAP  192           // max staged keys (window 64+100 -> <=6 tiles of 32)
#define SCALE 0.125f

typedef __attribute__((ext_vector_type(8))) short bf16x8;
typedef __attribute__((ext_vector_type(4))) float f32x4;

__device__ __forceinline__ unsigned int bf16_rne(float f) {
    unsigned int u = __float_as_uint(f);
    return (u + 0x7fffu + ((u >> 16) & 1u)) >> 16;
}
__device__ __forceinline__ unsigned int pk2(float lo, float hi) {
    return bf16_rne(lo) | (bf16_rne(hi) << 16);
}

// LDS: K  [192 keys][64 d] bf16, 128B rows, 16B slots, slot' = slot ^ (key&7)
//      V^T[64 d][192 keys] bf16, 384B rows, 16B slots, slot' = slot ^ (d&7)
//      P  [4 waves][16 q][40 k] bf16 (padded rows, per-wave scratch, no barrier)
__global__ __launch_bounds__(THREADS)
void lattn_mfma(const float* __restrict__ Q, const float* __restrict__ K,
                const float* __restrict__ V, float* __restrict__ O) {
    __shared__ unsigned short Ks[KCAP * 64];
    __shared__ unsigned short Vs[DIM * KCAP];
    __shared__ unsigned short Ps[4 * 16 * 40];

    // bijective XCD swizzle: each XCD gets a contiguous span of (bh, xb) blocks
    const int nwg = gridDim.x;                 // multiple of 8 (1024)
    const int cpx = nwg >> 3;
    const int bid = blockIdx.x;
    const int logical = (bid & 7) * cpx + (bid >> 3);
    const int bh = logical >> 6;               // 64 x-blocks per bh
    const int r0 = (logical & 63) * RB;

    const size_t base = (size_t)bh * (S_LEN * DIM);
    const float* Qg = Q + base;
    const float* Kg = K + base;
    const float* Vg = V + base;
    float*       Og = O + base;

    const int kstart = (r0 >= HALF) ? ((r0 - HALF) & ~31) : 0;
    const int kend   = min(S_LEN, r0 + RB + HALF);   // exclusive
    const int nstep  = (kend - kstart + 31) >> 5;    // <= 6
    const int nkeys  = nstep << 5;

    const int u = threadIdx.x;

    // ---- stage K -> bf16 LDS (row-major, slot-XOR) ----
    for (int idx = u; idx < (nkeys << 3); idx += THREADS) {
        const int krow = idx >> 3;
        const int oct  = idx & 7;
        const int kg   = kstart + krow;
        unsigned int w0, w1, w2, w3;
        if (kg < kend) {
            const float4 a = *(const float4*)(Kg + (size_t)kg * DIM + oct * 8);
            const float4 b = *(const float4*)(Kg + (size_t)kg * DIM + oct * 8 + 4);
            w0 = pk2(a.x, a.y); w1 = pk2(a.z, a.w);
            w2 = pk2(b.x, b.y); w3 = pk2(b.z, b.w);
        } else { w0 = w1 = w2 = w3 = 0u; }
        *(uint4*)(Ks + krow * 64 + ((oct ^ (krow & 7)) << 3)) = make_uint4(w0, w1, w2, w3);
    }

    // ---- stage V -> transposed bf16 LDS (pairs of keys per u32, slot-XOR) ----
    for (int idx = u; idx < (nkeys << 2); idx += THREADS) {
        const int kp = (idx & 31) | ((idx >> 8) << 5);   // key-pair index
        const int d0 = ((idx >> 5) & 7) * 8;
        const int k0 = kp * 2;
        const int kg = kstart + k0;
        unsigned int pw[8];
        if (kg < kend) {                                  // kend even -> pair never straddles
            const float* va = Vg + (size_t)kg * DIM + d0;
            const float* vb = va + DIM;
            float a0[8], a1[8];
            *(float4*)a0 = *(const float4*)va;  *(float4*)(a0 + 4) = *(const float4*)(va + 4);
            *(float4*)a1 = *(const float4*)vb;  *(float4*)(a1 + 4) = *(const float4*)(vb + 4);
            #pragma unroll
            for (int j = 0; j < 8; ++j) pw[j] = pk2(a0[j], a1[j]);
        } else {
            #pragma unroll
            for (int j = 0; j < 8; ++j) pw[j] = 0u;
        }
        #pragma unroll
        for (int j = 0; j < 8; ++j) {
            const int d  = d0 + j;
            const int sl = (k0 >> 3) ^ (d & 7);
            *(unsigned int*)(Vs + d * KCAP + sl * 8 + (k0 & 7)) = pw[j];
        }
    }

    // ---- Q^T B-fragments straight from global (scale folded) ----
    const int lane = u & 63;
    const int wv_  = u >> 6;
    const int g  = lane >> 4;
    const int cc = lane & 15;
    const int qlo = r0 + WQ * wv_;

    bf16x8 qf[2];
    #pragma unroll
    for (int ds = 0; ds < 2; ++ds) {
        const float* src = Qg + (size_t)(qlo + cc) * DIM + ds * 32 + g * 8;
        const float4 a = *(const float4*)src;
        const float4 b = *(const float4*)(src + 4);
        uint4 t = make_uint4(pk2(a.x * SCALE, a.y * SCALE), pk2(a.z * SCALE, a.w * SCALE),
                             pk2(b.x * SCALE, b.y * SCALE), pk2(b.z * SCALE, b.w * SCALE));
        qf[ds] = __builtin_bit_cast(bf16x8, t);
    }

    __syncthreads();

    f32x4 oacc[4] = {};
    float denom = 0.f;

    // per-wave step range (only tiles intersecting this wave's band)
    int lo = (qlo >= HALF) ? (qlo - HALF) : 0;
    lo = max(kstart, lo & ~31);
    const int t0 = (lo - kstart) >> 5;
    const int hi = min(kend, qlo + WQ - 1 + HALF + 1);
    const int t1 = (hi - kstart + 31) >> 5;

    unsigned short* Pw = Ps + wv_ * (16 * 40);

    for (int st = t0; st < t1; ++st) {
        const int kb = st << 5;   // local key base of this 32-key step

        // --- swapped QK^T: S^T[key][q] ---
        f32x4 sacc[2] = {};       // [kt]
        #pragma unroll
        for (int ds = 0; ds < 2; ++ds) {
            #pragma unroll
            for (int kt = 0; kt < 2; ++kt) {
                const int krow = kb + kt * 16 + cc;
                const int sl   = (ds * 4 + g) ^ (krow & 7);
                const bf16x8 ka = *(const bf16x8*)(Ks + krow * 64 + sl * 8);
                sacc[kt] = __builtin_amdgcn_mfma_f32_16x16x32_bf16(ka, qf[ds], sacc[kt], 0, 0, 0);
            }
        }

        // --- mask + exp + P write (per-wave LDS, no barrier) ---
        const int q = qlo + cc;
        #pragma unroll
        for (int kt = 0; kt < 2; ++kt) {
            float w4[4];
            const int keyb = kstart + kb + kt * 16 + g * 4;
            #pragma unroll
            for (int r = 0; r < 4; ++r) {
                const int key = keyb + r;
                const float e = __expf(sacc[kt][r]);
                const int dd  = key - q;
                const bool ok = (dd >= -HALF) && (dd <= HALF) && (key < S_LEN);
                w4[r] = ok ? e : 0.f;
                denom += w4[r];
            }
            *(uint2*)(Pw + cc * 40 + kt * 16 + g * 4) = make_uint2(pk2(w4[0], w4[1]), pk2(w4[2], w4[3]));
        }

        // --- PV: O^T += V^T x P^T ---
        const bf16x8 pf = *(const bf16x8*)(Pw + cc * 40 + g * 8);
        #pragma unroll
        for (int dt = 0; dt < 4; ++dt) {
            const int d  = dt * 16 + cc;
            const int sl = ((kb >> 3) + g) ^ (d & 7);
            const bf16x8 vf = *(const bf16x8*)(Vs + d * KCAP + sl * 8);
            oacc[dt] = __builtin_amdgcn_mfma_f32_16x16x32_bf16(vf, pf, oacc[dt], 0, 0, 0);
        }
    }

    // ---- normalize + store ----
    denom += __shfl_xor(denom, 16);
    denom += __shfl_xor(denom, 32);
    const float rinv = 1.f / denom;
    float* dst = Og + (size_t)(qlo + cc) * DIM;
    #pragma unroll
    for (int dt = 0; dt < 4; ++dt) {
        const f32x4 o = oacc[dt];
        *(float4*)(dst + dt * 16 + g * 4) =
            make_float4(o[0] * rinv, o[1] * rinv, o[2] * rinv, o[3] * rinv);
    }
}

extern "C" void kernel_launch(void* const* d_in, const int* in_sizes, int n_in,
                              void* d_out, int out_size, void* d_ws, size_t ws_size,
                              hipStream_t stream) {
    const float* q = (const float*)d_in[0];
    const float* k = (const float*)d_in[1];
    const float* v = (const float*)d_in[2];
    float* o = (float*)d_out;
    const int nbh = in_sizes[0] / (S_LEN * DIM);      // B*H = 16
    dim3 grid((S_LEN / RB) * nbh);                    // 1024, multiple of 8
    lattn_mfma<<<grid, THREADS, 0, stream>>>(q, k, v, o);
}

// Round 3
// 21.840 us; speedup vs baseline: 4.4187x; 1.2144x over previous
//
#include <hip/hip_runtime.h>

#define S_LEN 4096
#define DIM   64
#define HALF  50
#define RB    256           // query rows per block
#define WQ    16            // query rows per wave (16 waves)
#define THREADS 1024
#define KCAP  384           // max staged keys: span <= 370 -> 12 tiles of 32
#define SCALE 0.125f

typedef __attribute__((ext_vector_type(8))) short bf16x8;
typedef __attribute__((ext_vector_type(4))) float f32x4;

__device__ __forceinline__ unsigned int bf16_rne(float f) {
    unsigned int u = __float_as_uint(f);
    return (u + 0x7fffu + ((u >> 16) & 1u)) >> 16;
}
__device__ __forceinline__ unsigned int pk2(float lo, float hi) {
    return bf16_rne(lo) | (bf16_rne(hi) << 16);
}

// LDS: K  [384 keys][64 d] bf16, 128B rows, 16B slots, slot' = slot ^ (key&7)
//      V^T[64 d][384 keys] bf16, 768B rows, 16B slots, slot' = slot ^ (d&7)
//      P  [16 waves][16 q][40 k] bf16 (per-wave scratch, wave-internal sync only)
__global__ __launch_bounds__(THREADS)
void lattn_mfma(const float* __restrict__ Q, const float* __restrict__ K,
                const float* __restrict__ V, float* __restrict__ O) {
    __shared__ unsigned short Ks[KCAP * 64];
    __shared__ unsigned short Vs[DIM * KCAP];
    __shared__ unsigned short Ps[16 * 16 * 40];

    // bijective XCD swizzle: consecutive r0-blocks land on the same XCD's L2
    const int nwg = gridDim.x;                 // 256
    const int cpx = nwg >> 3;
    const int bid = blockIdx.x;
    const int logical = (bid & 7) * cpx + (bid >> 3);
    const int bh = logical >> 4;               // 16 x-blocks per bh
    const int r0 = (logical & 15) * RB;

    const size_t base = (size_t)bh * (S_LEN * DIM);
    const float* Qg = Q + base;
    const float* Kg = K + base;
    const float* Vg = V + base;
    float*       Og = O + base;

    const int kstart = (r0 >= HALF) ? ((r0 - HALF) & ~31) : 0;
    const int kend   = min(S_LEN, r0 + RB + HALF);   // exclusive
    const int nstep  = (kend - kstart + 31) >> 5;    // <= 12
    const int nkeys  = nstep << 5;

    const int u = threadIdx.x;

    // ---- stage K -> bf16 LDS (row-major, slot-XOR) ----
    for (int idx = u; idx < (nkeys << 3); idx += THREADS) {
        const int krow = idx >> 3;
        const int oct  = idx & 7;
        const int kg   = kstart + krow;
        unsigned int w0, w1, w2, w3;
        if (kg < kend) {
            const float4 a = *(const float4*)(Kg + (size_t)kg * DIM + oct * 8);
            const float4 b = *(const float4*)(Kg + (size_t)kg * DIM + oct * 8 + 4);
            w0 = pk2(a.x, a.y); w1 = pk2(a.z, a.w);
            w2 = pk2(b.x, b.y); w3 = pk2(b.z, b.w);
        } else { w0 = w1 = w2 = w3 = 0u; }
        *(uint4*)(Ks + krow * 64 + ((oct ^ (krow & 7)) << 3)) = make_uint4(w0, w1, w2, w3);
    }

    // ---- stage V -> transposed bf16 LDS (pairs of keys per u32, slot-XOR) ----
    for (int idx = u; idx < (nkeys << 2); idx += THREADS) {
        const int kp = idx >> 3;                 // key-pair index
        const int m  = idx & 7;                  // d-octet owner (and rotation seed)
        const int d0 = m * 8;
        const int k0 = kp * 2;
        const int kg = kstart + k0;
        unsigned int pw[8];
        if (kg < kend) {                          // kend even -> pair never straddles
            const float* va = Vg + (size_t)kg * DIM + d0;
            const float* vb = va + DIM;
            float a0[8], a1[8];
            *(float4*)a0 = *(const float4*)va;  *(float4*)(a0 + 4) = *(const float4*)(va + 4);
            *(float4*)a1 = *(const float4*)vb;  *(float4*)(a1 + 4) = *(const float4*)(vb + 4);
            #pragma unroll
            for (int j = 0; j < 8; ++j) pw[j] = pk2(a0[j], a1[j]);
        } else {
            #pragma unroll
            for (int j = 0; j < 8; ++j) pw[j] = 0u;
        }
        // rotated write order: the 8 lanes sharing this key-pair hit 8 distinct banks
        #pragma unroll
        for (int j = 0; j < 8; ++j) {
            const int jj = (j + m) & 7;
            const int d  = d0 + jj;
            const int sl = (k0 >> 3) ^ (d & 7);
            *(unsigned int*)(Vs + d * KCAP + sl * 8 + (k0 & 7)) = pw[jj];
        }
    }

    // ---- Q^T B-fragments straight from global (scale folded) ----
    const int lane = u & 63;
    const int wv_  = u >> 6;
    const int g  = lane >> 4;
    const int cc = lane & 15;
    const int qlo = r0 + WQ * wv_;

    bf16x8 qf[2];
    #pragma unroll
    for (int ds = 0; ds < 2; ++ds) {
        const float* src = Qg + (size_t)(qlo + cc) * DIM + ds * 32 + g * 8;
        const float4 a = *(const float4*)src;
        const float4 b = *(const float4*)(src + 4);
        uint4 t = make_uint4(pk2(a.x * SCALE, a.y * SCALE), pk2(a.z * SCALE, a.w * SCALE),
                             pk2(b.x * SCALE, b.y * SCALE), pk2(b.z * SCALE, b.w * SCALE));
        qf[ds] = __builtin_bit_cast(bf16x8, t);
    }

    __syncthreads();

    f32x4 oacc[4] = {};
    float denom = 0.f;

    // per-wave step range (only tiles intersecting this wave's band)
    int lo = (qlo >= HALF) ? (qlo - HALF) : 0;
    lo = max(kstart, lo & ~31);
    const int t0 = (lo - kstart) >> 5;
    const int hi = min(kend, qlo + WQ - 1 + HALF + 1);
    const int t1 = (hi - kstart + 31) >> 5;

    unsigned short* Pw = Ps + wv_ * (16 * 40);

    for (int st = t0; st < t1; ++st) {
        const int kb = st << 5;   // local key base of this 32-key step

        // --- swapped QK^T: S^T[key][q] ---
        f32x4 sacc[2] = {};       // [kt]
        #pragma unroll
        for (int ds = 0; ds < 2; ++ds) {
            #pragma unroll
            for (int kt = 0; kt < 2; ++kt) {
                const int krow = kb + kt * 16 + cc;
                const int sl   = (ds * 4 + g) ^ (krow & 7);
                const bf16x8 ka = *(const bf16x8*)(Ks + krow * 64 + sl * 8);
                sacc[kt] = __builtin_amdgcn_mfma_f32_16x16x32_bf16(ka, qf[ds], sacc[kt], 0, 0, 0);
            }
        }

        // --- mask + exp + P write (per-wave LDS, no barrier) ---
        const int q = qlo + cc;
        #pragma unroll
        for (int kt = 0; kt < 2; ++kt) {
            float w4[4];
            const int keyb = kstart + kb + kt * 16 + g * 4;
            #pragma unroll
            for (int r = 0; r < 4; ++r) {
                const int key = keyb + r;
                const float e = __expf(sacc[kt][r]);
                const int dd  = key - q;
                const bool ok = (dd >= -HALF) && (dd <= HALF) && (key < S_LEN);
                w4[r] = ok ? e : 0.f;
                denom += w4[r];
            }
            *(uint2*)(Pw + cc * 40 + kt * 16 + g * 4) = make_uint2(pk2(w4[0], w4[1]), pk2(w4[2], w4[3]));
        }

        // --- PV: O^T += V^T x P^T ---
        const bf16x8 pf = *(const bf16x8*)(Pw + cc * 40 + g * 8);
        #pragma unroll
        for (int dt = 0; dt < 4; ++dt) {
            const int d  = dt * 16 + cc;
            const int sl = ((kb >> 3) + g) ^ (d & 7);
            const bf16x8 vf = *(const bf16x8*)(Vs + d * KCAP + sl * 8);
            oacc[dt] = __builtin_amdgcn_mfma_f32_16x16x32_bf16(vf, pf, oacc[dt], 0, 0, 0);
        }
    }

    // ---- normalize + store ----
    denom += __shfl_xor(denom, 16);
    denom += __shfl_xor(denom, 32);
    const float rinv = 1.f / denom;
    float* dst = Og + (size_t)(qlo + cc) * DIM;
    #pragma unroll
    for (int dt = 0; dt < 4; ++dt) {
        const f32x4 o = oacc[dt];
        *(float4*)(dst + dt * 16 + g * 4) =
            make_float4(o[0] * rinv, o[1] * rinv, o[2] * rinv, o[3] * rinv);
    }
}

extern "C" void kernel_launch(void* const* d_in, const int* in_sizes, int n_in,
                              void* d_out, int out_size, void* d_ws, size_t ws_size,
                              hipStream_t stream) {
    const float* q = (const float*)d_in[0];
    const float* k = (const float*)d_in[1];
    const float* v = (const float*)d_in[2];
    float* o = (float*)d_out;
    const int nbh = in_sizes[0] / (S_LEN * DIM);      // B*H = 16
    dim3 grid((S_LEN / RB) * nbh);                    // 256 blocks = 1/CU
    lattn_mfma<<<grid, THREADS, 0, stream>>>(q, k, v, o);
}